// Round 2
// baseline (1163.717 us; speedup 1.0000x reference)
//
#include <hip/hip_runtime.h>
#include <math.h>

// MHA block, fp32: qkv SGEMM -> flash attention -> proj SGEMM.
// B=2 T=2048 C=1024 H=16 D=64. All float32 per the reference dtypes.

// ---------------------------------------------------------------------------
// C[M,N] = A[M,K] @ Bt[N,K]^T  (row-major, fp32). 128x128 tile, BK=8,
// 256 threads, 8x8 outputs/thread.
// ---------------------------------------------------------------------------
__global__ __launch_bounds__(256) void sgemm_bt(
    const float* __restrict__ A, const float* __restrict__ Bt,
    float* __restrict__ C, int M, int N, int K)
{
    __shared__ float As[8][132];   // [k][m], padded
    __shared__ float Bs[8][132];   // [k][n], padded

    const int tid = threadIdx.x;
    const int tx  = tid & 15;      // n-block
    const int ty  = tid >> 4;      // m-block
    const int bm  = blockIdx.y * 128;
    const int bn  = blockIdx.x * 128;
    const int lr  = tid >> 1;          // 0..127 staging row
    const int lc  = (tid & 1) * 4;     // 0 or 4 staging k-offset

    float acc[8][8];
#pragma unroll
    for (int i = 0; i < 8; ++i)
#pragma unroll
        for (int j = 0; j < 8; ++j) acc[i][j] = 0.f;

    for (int k0 = 0; k0 < K; k0 += 8) {
        const float4 av = *(const float4*)&A [(size_t)(bm + lr) * K + k0 + lc];
        const float4 bv = *(const float4*)&Bt[(size_t)(bn + lr) * K + k0 + lc];
        As[lc + 0][lr] = av.x; As[lc + 1][lr] = av.y;
        As[lc + 2][lr] = av.z; As[lc + 3][lr] = av.w;
        Bs[lc + 0][lr] = bv.x; Bs[lc + 1][lr] = bv.y;
        Bs[lc + 2][lr] = bv.z; Bs[lc + 3][lr] = bv.w;
        __syncthreads();

#pragma unroll
        for (int kk = 0; kk < 8; ++kk) {
            float a[8], b[8];
            *(float4*)(a)     = *(const float4*)&As[kk][ty * 8];
            *(float4*)(a + 4) = *(const float4*)&As[kk][ty * 8 + 4];
            *(float4*)(b)     = *(const float4*)&Bs[kk][tx * 8];
            *(float4*)(b + 4) = *(const float4*)&Bs[kk][tx * 8 + 4];
#pragma unroll
            for (int i = 0; i < 8; ++i)
#pragma unroll
                for (int j = 0; j < 8; ++j)
                    acc[i][j] = fmaf(a[i], b[j], acc[i][j]);
        }
        __syncthreads();
    }

#pragma unroll
    for (int i = 0; i < 8; ++i) {
        float* cp = &C[(size_t)(bm + ty * 8 + i) * N + bn + tx * 8];
        float4 c0 = {acc[i][0], acc[i][1], acc[i][2], acc[i][3]};
        float4 c1 = {acc[i][4], acc[i][5], acc[i][6], acc[i][7]};
        *(float4*)(cp)     = c0;
        *(float4*)(cp + 4) = c1;
    }
}

// ---------------------------------------------------------------------------
// fp32 flash attention. Block = 256 threads per (b, h, 64-row q tile).
// Thread (tx,ty) owns S rows ty*4.., cols tx*4.. ; O rows ty*4.., d-cols tx*4..
// KP buffer aliases K-tile (S phase) and P (PV phase) to stay under 64KB LDS.
// ---------------------------------------------------------------------------
__global__ __launch_bounds__(256) void attn_fp32(
    const float* __restrict__ qkv, float* __restrict__ y)
{
    constexpr int T = 2048;
    __shared__ float Qs[64][68];
    __shared__ float KP[64][68];   // K tile, then reused for P
    __shared__ float Vs[64][68];

    const int b  = blockIdx.z;
    const int h  = blockIdx.y;
    const int q0 = blockIdx.x * 64;

    const int tid = threadIdx.x;
    const int tx  = tid & 15;
    const int ty  = tid >> 4;

    const float* base = qkv + (size_t)b * T * 3072;

    // stage Q once: 64 rows x 64 d
    {
        const int r = tid >> 2, c0 = (tid & 3) * 16;
#pragma unroll
        for (int c = 0; c < 4; ++c)
            *(float4*)&Qs[r][c0 + c * 4] =
                *(const float4*)&base[(size_t)(q0 + r) * 3072 + h * 64 + c0 + c * 4];
    }

    float m_i[4], l_i[4], accO[4][4];
#pragma unroll
    for (int i = 0; i < 4; ++i) {
        m_i[i] = -INFINITY; l_i[i] = 0.f;
#pragma unroll
        for (int j = 0; j < 4; ++j) accO[i][j] = 0.f;
    }

    for (int j0 = 0; j0 <= q0; j0 += 64) {
        // ---- stage K, V tiles (coalesced float4) ----
        {
            const int r = tid >> 2, c0 = (tid & 3) * 16;
            const size_t rowb = (size_t)(j0 + r) * 3072 + h * 64;
#pragma unroll
            for (int c = 0; c < 4; ++c) {
                *(float4*)&KP[r][c0 + c * 4] = *(const float4*)&base[rowb + 1024 + c0 + c * 4];
                *(float4*)&Vs[r][c0 + c * 4] = *(const float4*)&base[rowb + 2048 + c0 + c * 4];
            }
        }
        __syncthreads();   // Q (first iter) + K/V visible

        // ---- S = Q K^T * 0.125, causal mask on diagonal tile ----
        float s[4][4];
#pragma unroll
        for (int i = 0; i < 4; ++i)
#pragma unroll
            for (int j = 0; j < 4; ++j) s[i][j] = 0.f;

        for (int dd = 0; dd < 64; dd += 4) {
            float qa[4][4], kb[4][4];
#pragma unroll
            for (int i = 0; i < 4; ++i)
                *(float4*)qa[i] = *(const float4*)&Qs[ty * 4 + i][dd];
#pragma unroll
            for (int j = 0; j < 4; ++j)
                *(float4*)kb[j] = *(const float4*)&KP[tx * 4 + j][dd];
#pragma unroll
            for (int i = 0; i < 4; ++i)
#pragma unroll
                for (int j = 0; j < 4; ++j)
#pragma unroll
                    for (int c = 0; c < 4; ++c)
                        s[i][j] = fmaf(qa[i][c], kb[j][c], s[i][j]);
        }

        const bool diag = (j0 == q0);
        float mx[4];
#pragma unroll
        for (int i = 0; i < 4; ++i) mx[i] = -INFINITY;
#pragma unroll
        for (int i = 0; i < 4; ++i)
#pragma unroll
            for (int j = 0; j < 4; ++j) {
                float v = s[i][j] * 0.125f;
                if (diag && (tx * 4 + j) > (ty * 4 + i)) v = -INFINITY;
                s[i][j] = v;
                mx[i] = fmaxf(mx[i], v);
            }
        // reduce over the 16 tx-lanes (contiguous 16-lane subgroup of the wave)
#pragma unroll
        for (int o = 8; o >= 1; o >>= 1)
#pragma unroll
            for (int i = 0; i < 4; ++i) mx[i] = fmaxf(mx[i], __shfl_xor(mx[i], o));

        float alpha[4], rs[4];
#pragma unroll
        for (int i = 0; i < 4; ++i) {
            const float mn = fmaxf(m_i[i], mx[i]);
            alpha[i] = __expf(m_i[i] - mn);   // exp(-inf)=0 on first tile
            m_i[i] = mn;
            rs[i] = 0.f;
        }
#pragma unroll
        for (int i = 0; i < 4; ++i)
#pragma unroll
            for (int j = 0; j < 4; ++j) {
                const float p = __expf(s[i][j] - m_i[i]);
                s[i][j] = p;
                rs[i] += p;
            }
#pragma unroll
        for (int o = 8; o >= 1; o >>= 1)
#pragma unroll
            for (int i = 0; i < 4; ++i) rs[i] += __shfl_xor(rs[i], o);
#pragma unroll
        for (int i = 0; i < 4; ++i) l_i[i] = l_i[i] * alpha[i] + rs[i];

        __syncthreads();   // all K reads done before P overwrites KP

        // ---- write P over the K tile ----
#pragma unroll
        for (int i = 0; i < 4; ++i)
#pragma unroll
            for (int j = 0; j < 4; ++j)
                KP[ty * 4 + i][tx * 4 + j] = s[i][j];
#pragma unroll
        for (int i = 0; i < 4; ++i)
#pragma unroll
            for (int j = 0; j < 4; ++j) accO[i][j] *= alpha[i];
        __syncthreads();   // P visible to all

        // ---- O += P @ V ----
        for (int kv = 0; kv < 64; kv += 4) {
            float pa[4][4], vb[4][4];
#pragma unroll
            for (int i = 0; i < 4; ++i)
                *(float4*)pa[i] = *(const float4*)&KP[ty * 4 + i][kv];
#pragma unroll
            for (int c = 0; c < 4; ++c)
                *(float4*)vb[c] = *(const float4*)&Vs[kv + c][tx * 4];
#pragma unroll
            for (int i = 0; i < 4; ++i)
#pragma unroll
                for (int j = 0; j < 4; ++j)
#pragma unroll
                    for (int c = 0; c < 4; ++c)
                        accO[i][j] = fmaf(pa[i][c], vb[c][j], accO[i][j]);
        }
        __syncthreads();   // before next tile's staging overwrites KP/Vs
    }

    // ---- epilogue: y[b, q, h*64 + d] = O / l ----
#pragma unroll
    for (int i = 0; i < 4; ++i) {
        const float inv = 1.f / l_i[i];
        float4 o = {accO[i][0] * inv, accO[i][1] * inv,
                    accO[i][2] * inv, accO[i][3] * inv};
        *(float4*)&y[((size_t)b * T + q0 + ty * 4 + i) * 1024 + h * 64 + tx * 4] = o;
    }
}

// ---------------------------------------------------------------------------
extern "C" void kernel_launch(void* const* d_in, const int* in_sizes, int n_in,
                              void* d_out, int out_size, void* d_ws, size_t ws_size,
                              hipStream_t stream)
{
    const float* x      = (const float*)d_in[0];
    const float* w_attn = (const float*)d_in[1];
    const float* w_proj = (const float*)d_in[2];
    // d_in[3] = mask (int32 tril) — statically causal, unused.

    float* out = (float*)d_out;
    float* qkv = (float*)d_ws;                       // [4096, 3072] fp32
    float* y   = qkv + (size_t)4096 * 3072;          // [4096, 1024] fp32

    // qkv = x @ w_attn^T : M=4096 N=3072 K=1024
    sgemm_bt<<<dim3(3072 / 128, 4096 / 128), 256, 0, stream>>>(x, w_attn, qkv, 4096, 3072, 1024);
    // flash attention
    attn_fp32<<<dim3(2048 / 64, 16, 2), 256, 0, stream>>>(qkv, y);
    // out = y @ w_proj^T : M=4096 N=1024 K=1024
    sgemm_bt<<<dim3(1024 / 128, 4096 / 128), 256, 0, stream>>>(y, w_proj, out, 4096, 1024, 1024);
}

// Round 3
// 306.187 us; speedup vs baseline: 3.8007x; 3.8007x over previous
//
#include <hip/hip_runtime.h>
#include <hip/hip_bf16.h>
#include <math.h>

// MHA block: fp32 inputs -> bf16 MFMA pipeline -> fp32 output.
// B=2 T=2048 C=1024 H=16 D=64.

typedef __attribute__((ext_vector_type(4))) float floatx4;
typedef __attribute__((ext_vector_type(8))) __bf16 bf16x8;

#define MFMA_BF16(a, b, c) __builtin_amdgcn_mfma_f32_16x16x32_bf16((a), (b), (c), 0, 0, 0)

__device__ inline uint4 cvt8_f32_bf16(const float4 a, const float4 b) {
    union { __hip_bfloat16 h[8]; uint4 u; } c;
    c.h[0] = __float2bfloat16(a.x); c.h[1] = __float2bfloat16(a.y);
    c.h[2] = __float2bfloat16(a.z); c.h[3] = __float2bfloat16(a.w);
    c.h[4] = __float2bfloat16(b.x); c.h[5] = __float2bfloat16(b.y);
    c.h[6] = __float2bfloat16(b.z); c.h[7] = __float2bfloat16(b.w);
    return c.u;
}

// ---------------------------------------------------------------------------
// C[M,N] = A[M,K] @ Bt[N,K]^T via bf16 MFMA, fp32 accumulate.
// A: fp32 or bf16 (A_F32). Bt: fp32 (converted during staging). C: fp32 or bf16.
// 128x128 block tile, 4 waves of 64x64, BK=32.
// ---------------------------------------------------------------------------
template<bool A_F32, bool C_F32>
__global__ __launch_bounds__(256) void gemm_bt_mfma(
    const void* __restrict__ Av, const float* __restrict__ Bt,
    void* __restrict__ Cv, int M, int N, int K)
{
    __shared__ __hip_bfloat16 As[128][40];  // 80B rows: 16B-aligned, 2-way alias only
    __shared__ __hip_bfloat16 Bs[128][40];

    const int tid  = threadIdx.x;
    const int wave = tid >> 6;
    const int lane = tid & 63;
    const int quad = lane >> 4;
    const int l15  = lane & 15;
    const int wrow = wave >> 1;
    const int wcol = wave & 1;
    const int bm = blockIdx.y * 128;
    const int bn = blockIdx.x * 128;

    floatx4 acc[4][4];
#pragma unroll
    for (int i = 0; i < 4; ++i)
#pragma unroll
        for (int j = 0; j < 4; ++j)
            acc[i][j] = (floatx4){0.f, 0.f, 0.f, 0.f};

    const int lrow = tid >> 2;       // 0..63
    const int lcg  = (tid & 3) * 8;  // 0,8,16,24

    for (int k0 = 0; k0 < K; k0 += 32) {
#pragma unroll
        for (int r = 0; r < 2; ++r) {
            const int row = lrow + r * 64;
            // A tile
            if (A_F32) {
                const float* A = (const float*)Av;
                const float4 a0 = *(const float4*)&A[(size_t)(bm + row) * K + k0 + lcg];
                const float4 a1 = *(const float4*)&A[(size_t)(bm + row) * K + k0 + lcg + 4];
                *(uint4*)&As[row][lcg] = cvt8_f32_bf16(a0, a1);
            } else {
                const __hip_bfloat16* A = (const __hip_bfloat16*)Av;
                *(uint4*)&As[row][lcg] = *(const uint4*)&A[(size_t)(bm + row) * K + k0 + lcg];
            }
            // B tile (always fp32 weights)
            const float4 b0 = *(const float4*)&Bt[(size_t)(bn + row) * K + k0 + lcg];
            const float4 b1 = *(const float4*)&Bt[(size_t)(bn + row) * K + k0 + lcg + 4];
            *(uint4*)&Bs[row][lcg] = cvt8_f32_bf16(b0, b1);
        }
        __syncthreads();

        bf16x8 af[4], bfv[4];
#pragma unroll
        for (int i = 0; i < 4; ++i)
            af[i] = *(const bf16x8*)&As[wrow * 64 + i * 16 + l15][quad * 8];
#pragma unroll
        for (int j = 0; j < 4; ++j)
            bfv[j] = *(const bf16x8*)&Bs[wcol * 64 + j * 16 + l15][quad * 8];

#pragma unroll
        for (int i = 0; i < 4; ++i)
#pragma unroll
            for (int j = 0; j < 4; ++j)
                acc[i][j] = MFMA_BF16(af[i], bfv[j], acc[i][j]);
        __syncthreads();
    }

    // epilogue: C/D layout row = quad*4 + r, col = l15
#pragma unroll
    for (int i = 0; i < 4; ++i)
#pragma unroll
        for (int j = 0; j < 4; ++j)
#pragma unroll
            for (int r = 0; r < 4; ++r) {
                const int row = bm + wrow * 64 + i * 16 + quad * 4 + r;
                const int col = bn + wcol * 64 + j * 16 + l15;
                if (C_F32)
                    ((float*)Cv)[(size_t)row * N + col] = acc[i][j][r];
                else
                    ((__hip_bfloat16*)Cv)[(size_t)row * N + col] = __float2bfloat16(acc[i][j][r]);
            }
}

// ---------------------------------------------------------------------------
// Flash attention, bf16 MFMA, fp32 softmax state. One block (4 waves) per
// (b, h, 64-row q tile). qkv bf16 [B*T, 3072]: q|k|v at col 0|1024|2048.
// ---------------------------------------------------------------------------
__global__ __launch_bounds__(256) void attn_kernel(
    const __hip_bfloat16* __restrict__ qkv,
    __hip_bfloat16* __restrict__ y)
{
    constexpr int T = 2048;
    __shared__ __hip_bfloat16 Ks[64][72];   // K rows (d contiguous), 144B rows
    __shared__ __hip_bfloat16 Vt[64][72];   // V transposed: [d][kv]
    __shared__ __hip_bfloat16 Ps[64][72];   // P: C-layout -> A-layout round-trip

    const int b  = blockIdx.z;
    const int h  = blockIdx.y;
    const int q0 = (gridDim.x - 1 - blockIdx.x) * 64;   // long blocks first

    const int tid  = threadIdx.x;
    const int wave = tid >> 6;
    const int lane = tid & 63;
    const int quad = lane >> 4;
    const int l15  = lane & 15;

    const __hip_bfloat16* base = qkv + (size_t)b * T * 3072;

    // Q fragments (A-layout), held in registers for the whole q tile
    bf16x8 aq[2];
    {
        const int qrow = q0 + wave * 16 + l15;
#pragma unroll
        for (int kd = 0; kd < 2; ++kd)
            aq[kd] = *(const bf16x8*)&base[(size_t)qrow * 3072 + h * 64 + kd * 32 + quad * 8];
    }

    floatx4 acc_o[4];
#pragma unroll
    for (int jd = 0; jd < 4; ++jd) acc_o[jd] = (floatx4){0.f, 0.f, 0.f, 0.f};
    float m_i[4], l_i[4];
#pragma unroll
    for (int r = 0; r < 4; ++r) { m_i[r] = -INFINITY; l_i[r] = 0.f; }

    for (int j0 = 0; j0 <= q0; j0 += 64) {
        // ---- stage K tile (coalesced 16B) ----
        {
            const int row = tid >> 3;             // 0..31
            const int cg  = (tid & 7) * 8;        // 0..56
#pragma unroll
            for (int rr = 0; rr < 2; ++rr)
                *(uint4*)&Ks[row + rr * 32][cg] =
                    *(const uint4*)&base[(size_t)(j0 + row + rr * 32) * 3072 + 1024 + h * 64 + cg];
        }
        // ---- stage V transposed (coalesced global reads, scalar LDS writes) ----
        {
            const int d   = tid & 63;
            const int kvb = (tid >> 6) * 16;
#pragma unroll
            for (int rr = 0; rr < 16; ++rr) {
                const int kv = kvb + rr;
                Vt[d][kv] = base[(size_t)(j0 + kv) * 3072 + 2048 + h * 64 + d];
            }
        }
        __syncthreads();

        // ---- S = Q K^T (wave: 16 q-rows x 64 kv-cols) ----
        floatx4 s[4];
#pragma unroll
        for (int jt = 0; jt < 4; ++jt) s[jt] = (floatx4){0.f, 0.f, 0.f, 0.f};
#pragma unroll
        for (int jt = 0; jt < 4; ++jt)
#pragma unroll
            for (int kd = 0; kd < 2; ++kd) {
                bf16x8 bk = *(const bf16x8*)&Ks[jt * 16 + l15][kd * 32 + quad * 8];
                s[jt] = MFMA_BF16(aq[kd], bk, s[jt]);
            }

        // ---- scale + causal mask (diag tile) + online softmax ----
        const bool diag = (j0 == q0);
        float mx[4];
#pragma unroll
        for (int r = 0; r < 4; ++r) mx[r] = -INFINITY;
#pragma unroll
        for (int jt = 0; jt < 4; ++jt)
#pragma unroll
            for (int r = 0; r < 4; ++r) {
                float v = s[jt][r] * 0.125f;   // 1/sqrt(64)
                if (diag && (jt * 16 + l15) > (wave * 16 + quad * 4 + r)) v = -INFINITY;
                s[jt][r] = v;
                mx[r] = fmaxf(mx[r], v);
            }
#pragma unroll
        for (int o = 8; o >= 1; o >>= 1)
#pragma unroll
            for (int r = 0; r < 4; ++r) mx[r] = fmaxf(mx[r], __shfl_xor(mx[r], o));

        float alpha[4], rs[4];
#pragma unroll
        for (int r = 0; r < 4; ++r) {
            const float mn = fmaxf(m_i[r], mx[r]);
            alpha[r] = __expf(m_i[r] - mn);
            m_i[r] = mn;
            rs[r] = 0.f;
        }
#pragma unroll
        for (int jt = 0; jt < 4; ++jt)
#pragma unroll
            for (int r = 0; r < 4; ++r) {
                const float p = __expf(s[jt][r] - m_i[r]);
                s[jt][r] = p;
                rs[r] += p;
            }
#pragma unroll
        for (int o = 8; o >= 1; o >>= 1)
#pragma unroll
            for (int r = 0; r < 4; ++r) rs[r] += __shfl_xor(rs[r], o);
#pragma unroll
        for (int r = 0; r < 4; ++r) l_i[r] = l_i[r] * alpha[r] + rs[r];

        // ---- P (C-layout) -> LDS ----
#pragma unroll
        for (int jt = 0; jt < 4; ++jt)
#pragma unroll
            for (int r = 0; r < 4; ++r)
                Ps[wave * 16 + quad * 4 + r][jt * 16 + l15] = __float2bfloat16(s[jt][r]);
        __syncthreads();

        // ---- O = O*alpha + P @ V ----
#pragma unroll
        for (int jd = 0; jd < 4; ++jd)
#pragma unroll
            for (int r = 0; r < 4; ++r) acc_o[jd][r] *= alpha[r];
#pragma unroll
        for (int kk = 0; kk < 2; ++kk) {
            bf16x8 ap = *(const bf16x8*)&Ps[wave * 16 + l15][kk * 32 + quad * 8];
#pragma unroll
            for (int jd = 0; jd < 4; ++jd) {
                bf16x8 bv = *(const bf16x8*)&Vt[jd * 16 + l15][kk * 32 + quad * 8];
                acc_o[jd] = MFMA_BF16(ap, bv, acc_o[jd]);
            }
        }
        __syncthreads();   // protect Ks/Vt/Ps before next staging
    }

    // ---- epilogue: y[b, q, h*64 + d] ----
#pragma unroll
    for (int jd = 0; jd < 4; ++jd)
#pragma unroll
        for (int r = 0; r < 4; ++r) {
            const int row = q0 + wave * 16 + quad * 4 + r;
            const int col = h * 64 + jd * 16 + l15;
            y[((size_t)b * T + row) * 1024 + col] =
                __float2bfloat16(acc_o[jd][r] / l_i[r]);
        }
}

// ---------------------------------------------------------------------------
extern "C" void kernel_launch(void* const* d_in, const int* in_sizes, int n_in,
                              void* d_out, int out_size, void* d_ws, size_t ws_size,
                              hipStream_t stream)
{
    const float* x      = (const float*)d_in[0];
    const float* w_attn = (const float*)d_in[1];
    const float* w_proj = (const float*)d_in[2];
    // d_in[3] = mask (int32 tril) — statically causal, unused.

    float* out = (float*)d_out;
    __hip_bfloat16* qkv = (__hip_bfloat16*)d_ws;            // [4096, 3072] bf16
    __hip_bfloat16* y   = qkv + (size_t)4096 * 3072;        // [4096, 1024] bf16

    // qkv = bf16(x) @ bf16(w_attn)^T
    gemm_bt_mfma<true, false><<<dim3(3072 / 128, 4096 / 128), 256, 0, stream>>>(
        x, w_attn, qkv, 4096, 3072, 1024);
    // flash attention
    attn_kernel<<<dim3(2048 / 64, 16, 2), 256, 0, stream>>>(qkv, y);
    // out = y @ bf16(w_proj)^T  (fp32 out)
    gemm_bt_mfma<false, true><<<dim3(1024 / 128, 4096 / 128), 256, 0, stream>>>(
        y, w_proj, out, 4096, 1024, 1024);
}

// Round 4
// 237.197 us; speedup vs baseline: 4.9061x; 1.2909x over previous
//
#include <hip/hip_runtime.h>
#include <hip/hip_bf16.h>
#include <math.h>

// MHA block: fp32 in -> bf16 MFMA pipeline -> fp32 out.
// B=2 T=2048 C=1024 H=16 D=64.

typedef __attribute__((ext_vector_type(4))) float floatx4;
typedef __attribute__((ext_vector_type(8))) __bf16 bf16x8;

#define MFMA_BF16(a, b, c) __builtin_amdgcn_mfma_f32_16x16x32_bf16((a), (b), (c), 0, 0, 0)

// async global->LDS, 16B per lane; lds dest must be wave-uniform base (+lane*16 by HW)
typedef __attribute__((address_space(1))) const uint32_t* gas_t;
typedef __attribute__((address_space(3))) uint32_t* las_t;
__device__ inline void gl2lds16(const void* g, void* l) {
    __builtin_amdgcn_global_load_lds((gas_t)g, (las_t)l, 16, 0, 0);
}

__device__ inline uint4 cvt8_f32_bf16(const float4 a, const float4 b) {
    union { __hip_bfloat16 h[8]; uint4 u; } c;
    c.h[0] = __float2bfloat16(a.x); c.h[1] = __float2bfloat16(a.y);
    c.h[2] = __float2bfloat16(a.z); c.h[3] = __float2bfloat16(a.w);
    c.h[4] = __float2bfloat16(b.x); c.h[5] = __float2bfloat16(b.y);
    c.h[6] = __float2bfloat16(b.z); c.h[7] = __float2bfloat16(b.w);
    return c.u;
}

// ---------------------------------------------------------------------------
__global__ __launch_bounds__(256) void cvt_f32_bf16_k(
    const float* __restrict__ in, __hip_bfloat16* __restrict__ out, int n)
{
    const int i = (blockIdx.x * 256 + threadIdx.x) * 8;
    if (i < n) {
        const float4 a = *(const float4*)&in[i];
        const float4 b = *(const float4*)&in[i + 4];
        *(uint4*)&out[i] = cvt8_f32_bf16(a, b);
    }
}

// ---------------------------------------------------------------------------
// C[M,N] = A[M,K] @ Bt[N,K]^T, bf16 MFMA, m97-style global_load_lds staging.
// 128x128 tile, BK=32, unpadded LDS (required by global_load_lds contiguity).
// ---------------------------------------------------------------------------
template<bool C_F32>
__global__ __launch_bounds__(256) void gemm_bt_mfma(
    const __hip_bfloat16* __restrict__ A,
    const __hip_bfloat16* __restrict__ Bt,
    void* __restrict__ Cv, int M, int N, int K)
{
    __shared__ __hip_bfloat16 As[128][32];
    __shared__ __hip_bfloat16 Bs[128][32];

    const int tid  = threadIdx.x;
    const int wave = tid >> 6;
    const int lane = tid & 63;
    const int quad = lane >> 4;
    const int l15  = lane & 15;
    const int wrow = wave >> 1;
    const int wcol = wave & 1;
    const int bm = blockIdx.y * 128;
    const int bn = blockIdx.x * 128;

    floatx4 acc[4][4];
#pragma unroll
    for (int i = 0; i < 4; ++i)
#pragma unroll
        for (int j = 0; j < 4; ++j)
            acc[i][j] = (floatx4){0.f, 0.f, 0.f, 0.f};

    const int srow = lane >> 2;        // 0..15 within 16-row chunk
    const int scol = (lane & 3) * 8;   // elem col 0,8,16,24

    const __hip_bfloat16* Abase = A  + (size_t)bm * K;
    const __hip_bfloat16* Bbase = Bt + (size_t)bn * K;

    for (int k0 = 0; k0 < K; k0 += 32) {
#pragma unroll
        for (int c = 0; c < 2; ++c) {
            const int rbase = wave * 32 + c * 16;   // wave-uniform
            gl2lds16(&Abase[(size_t)(rbase + srow) * K + k0 + scol], &As[rbase][0]);
            gl2lds16(&Bbase[(size_t)(rbase + srow) * K + k0 + scol], &Bs[rbase][0]);
        }
        __syncthreads();

        bf16x8 af[4], bfv[4];
#pragma unroll
        for (int i = 0; i < 4; ++i)
            af[i] = *(const bf16x8*)&As[wrow * 64 + i * 16 + l15][quad * 8];
#pragma unroll
        for (int j = 0; j < 4; ++j)
            bfv[j] = *(const bf16x8*)&Bs[wcol * 64 + j * 16 + l15][quad * 8];

#pragma unroll
        for (int i = 0; i < 4; ++i)
#pragma unroll
            for (int j = 0; j < 4; ++j)
                acc[i][j] = MFMA_BF16(af[i], bfv[j], acc[i][j]);
        __syncthreads();
    }

#pragma unroll
    for (int i = 0; i < 4; ++i)
#pragma unroll
        for (int j = 0; j < 4; ++j)
#pragma unroll
            for (int r = 0; r < 4; ++r) {
                const int row = bm + wrow * 64 + i * 16 + quad * 4 + r;
                const int col = bn + wcol * 64 + j * 16 + l15;
                if (C_F32)
                    ((float*)Cv)[(size_t)row * N + col] = acc[i][j][r];
                else
                    ((__hip_bfloat16*)Cv)[(size_t)row * N + col] = __float2bfloat16(acc[i][j][r]);
            }
}

// ---------------------------------------------------------------------------
// Pre-transpose V: qkv[b,t,2048+h*64+d] -> VtT[(b*16+h)*64+d][t]
// ---------------------------------------------------------------------------
__global__ __launch_bounds__(256) void transpose_v(
    const __hip_bfloat16* __restrict__ qkv, __hip_bfloat16* __restrict__ VtT)
{
    __shared__ __hip_bfloat16 Ls[64][72];
    const int b = blockIdx.z, h = blockIdx.y, t0 = blockIdx.x * 64;
    const int tid = threadIdx.x;
    {
        const int r = tid >> 2, c = (tid & 3) * 16;
        const size_t g = ((size_t)(b * 2048 + t0 + r)) * 3072 + 2048 + h * 64 + c;
        *(uint4*)&Ls[r][c]     = *(const uint4*)&qkv[g];
        *(uint4*)&Ls[r][c + 8] = *(const uint4*)&qkv[g + 8];
    }
    __syncthreads();
    {
        const int d = tid >> 2, k0 = (tid & 3) * 16;
        __hip_bfloat16 tmp[16];
#pragma unroll
        for (int j = 0; j < 16; ++j) tmp[j] = Ls[k0 + j][d];
        const size_t g = ((size_t)((b * 16 + h) * 64 + d)) * 2048 + t0 + k0;
        *(uint4*)&VtT[g]     = *(uint4*)&tmp[0];
        *(uint4*)&VtT[g + 8] = *(uint4*)&tmp[8];
    }
}

// ---------------------------------------------------------------------------
// Flash attention, paired causal q-tiles for load balance.
// Block p handles q-tiles p and 31-p; K/V tile staged once, used by both.
// ---------------------------------------------------------------------------
struct QState {
    bf16x8  aq[2];
    float   m[4], l[4];
    floatx4 acc[4];
};

__device__ inline void attn_softmax_tile(
    QState& st, bool diag,
    const __hip_bfloat16 (*Ks)[72], __hip_bfloat16 (*Ps)[72],
    int wave, int quad, int l15)
{
    floatx4 s[4];
#pragma unroll
    for (int jt = 0; jt < 4; ++jt) s[jt] = (floatx4){0.f, 0.f, 0.f, 0.f};
#pragma unroll
    for (int jt = 0; jt < 4; ++jt)
#pragma unroll
        for (int kd = 0; kd < 2; ++kd) {
            bf16x8 bk = *(const bf16x8*)&Ks[jt * 16 + l15][kd * 32 + quad * 8];
            s[jt] = MFMA_BF16(st.aq[kd], bk, s[jt]);
        }

    float mx[4];
#pragma unroll
    for (int r = 0; r < 4; ++r) mx[r] = -INFINITY;
#pragma unroll
    for (int jt = 0; jt < 4; ++jt)
#pragma unroll
        for (int r = 0; r < 4; ++r) {
            float v = s[jt][r] * 0.125f;
            if (diag && (jt * 16 + l15) > (wave * 16 + quad * 4 + r)) v = -INFINITY;
            s[jt][r] = v;
            mx[r] = fmaxf(mx[r], v);
        }
#pragma unroll
    for (int o = 8; o >= 1; o >>= 1)
#pragma unroll
        for (int r = 0; r < 4; ++r) mx[r] = fmaxf(mx[r], __shfl_xor(mx[r], o));

    float alpha[4], rs[4];
#pragma unroll
    for (int r = 0; r < 4; ++r) {
        const float mn = fmaxf(st.m[r], mx[r]);
        alpha[r] = __expf(st.m[r] - mn);
        st.m[r] = mn;
        rs[r] = 0.f;
    }
#pragma unroll
    for (int jt = 0; jt < 4; ++jt)
#pragma unroll
        for (int r = 0; r < 4; ++r) {
            const float p = __expf(s[jt][r] - st.m[r]);
            s[jt][r] = p;
            rs[r] += p;
        }
#pragma unroll
    for (int o = 8; o >= 1; o >>= 1)
#pragma unroll
        for (int r = 0; r < 4; ++r) rs[r] += __shfl_xor(rs[r], o);
#pragma unroll
    for (int r = 0; r < 4; ++r) st.l[r] = st.l[r] * alpha[r] + rs[r];

#pragma unroll
    for (int jt = 0; jt < 4; ++jt)
#pragma unroll
        for (int r = 0; r < 4; ++r)
            Ps[wave * 16 + quad * 4 + r][jt * 16 + l15] = __float2bfloat16(s[jt][r]);

#pragma unroll
    for (int jd = 0; jd < 4; ++jd)
#pragma unroll
        for (int r = 0; r < 4; ++r) st.acc[jd][r] *= alpha[r];
}

__device__ inline void attn_pv_tile(
    QState& st, const __hip_bfloat16 (*Ps)[72], const __hip_bfloat16 (*Vt)[72],
    int wave, int quad, int l15)
{
#pragma unroll
    for (int kk = 0; kk < 2; ++kk) {
        bf16x8 ap = *(const bf16x8*)&Ps[wave * 16 + l15][kk * 32 + quad * 8];
#pragma unroll
        for (int jd = 0; jd < 4; ++jd) {
            bf16x8 bv = *(const bf16x8*)&Vt[jd * 16 + l15][kk * 32 + quad * 8];
            st.acc[jd] = MFMA_BF16(ap, bv, st.acc[jd]);
        }
    }
}

__global__ __launch_bounds__(256) void attn_kernel(
    const __hip_bfloat16* __restrict__ qkv,
    const __hip_bfloat16* __restrict__ VtT,
    __hip_bfloat16* __restrict__ y)
{
    constexpr int T = 2048;
    __shared__ __hip_bfloat16 Ks[64][72];
    __shared__ __hip_bfloat16 Vt[64][72];
    __shared__ __hip_bfloat16 PsA[64][72];
    __shared__ __hip_bfloat16 PsB[64][72];

    const int b = blockIdx.z, h = blockIdx.y, p = blockIdx.x;
    const int q0A = p * 64;
    const int q0B = (31 - p) * 64;

    const int tid  = threadIdx.x;
    const int wave = tid >> 6;
    const int lane = tid & 63;
    const int quad = lane >> 4;
    const int l15  = lane & 15;

    const __hip_bfloat16* base  = qkv + (size_t)b * T * 3072;
    const __hip_bfloat16* vbase = VtT + (size_t)((b * 16 + h) * 64) * 2048;

    QState A, Bq;
#pragma unroll
    for (int kd = 0; kd < 2; ++kd) {
        A.aq[kd]  = *(const bf16x8*)&base[(size_t)(q0A + wave * 16 + l15) * 3072 + h * 64 + kd * 32 + quad * 8];
        Bq.aq[kd] = *(const bf16x8*)&base[(size_t)(q0B + wave * 16 + l15) * 3072 + h * 64 + kd * 32 + quad * 8];
    }
#pragma unroll
    for (int r = 0; r < 4; ++r) {
        A.m[r] = -INFINITY; A.l[r] = 0.f;
        Bq.m[r] = -INFINITY; Bq.l[r] = 0.f;
        A.acc[r] = (floatx4){0.f, 0.f, 0.f, 0.f};
        Bq.acc[r] = (floatx4){0.f, 0.f, 0.f, 0.f};
    }

    for (int j0 = 0; j0 <= q0B; j0 += 64) {
        const bool actA = (j0 <= q0A);
        // stage K rows and V^T rows (16B vector, conflict-free-ish)
        {
            const int r = tid >> 2, cg = (tid & 3) * 16;
            const size_t kg = (size_t)(j0 + r) * 3072 + 1024 + h * 64 + cg;
            *(uint4*)&Ks[r][cg]     = *(const uint4*)&base[kg];
            *(uint4*)&Ks[r][cg + 8] = *(const uint4*)&base[kg + 8];
            const size_t vg = (size_t)r * 2048 + j0 + cg;
            *(uint4*)&Vt[r][cg]     = *(const uint4*)&vbase[vg];
            *(uint4*)&Vt[r][cg + 8] = *(const uint4*)&vbase[vg + 8];
        }
        __syncthreads();

        attn_softmax_tile(Bq, j0 == q0B, Ks, PsB, wave, quad, l15);
        if (actA) attn_softmax_tile(A, j0 == q0A, Ks, PsA, wave, quad, l15);
        __syncthreads();

        attn_pv_tile(Bq, PsB, Vt, wave, quad, l15);
        if (actA) attn_pv_tile(A, PsA, Vt, wave, quad, l15);
        __syncthreads();
    }

    // epilogue
#pragma unroll
    for (int jd = 0; jd < 4; ++jd)
#pragma unroll
        for (int r = 0; r < 4; ++r) {
            const int col = h * 64 + jd * 16 + l15;
            const int rowA = q0A + wave * 16 + quad * 4 + r;
            y[((size_t)b * T + rowA) * 1024 + col] = __float2bfloat16(A.acc[jd][r] / A.l[r]);
            const int rowB = q0B + wave * 16 + quad * 4 + r;
            y[((size_t)b * T + rowB) * 1024 + col] = __float2bfloat16(Bq.acc[jd][r] / Bq.l[r]);
        }
}

// ---------------------------------------------------------------------------
extern "C" void kernel_launch(void* const* d_in, const int* in_sizes, int n_in,
                              void* d_out, int out_size, void* d_ws, size_t ws_size,
                              hipStream_t stream)
{
    const float* x      = (const float*)d_in[0];
    const float* w_attn = (const float*)d_in[1];
    const float* w_proj = (const float*)d_in[2];
    // d_in[3] = mask (tril) — statically causal, unused.

    float* out = (float*)d_out;
    __hip_bfloat16* xb  = (__hip_bfloat16*)d_ws;                 // 4096x1024
    __hip_bfloat16* wab = xb  + (size_t)4096 * 1024;             // 3072x1024
    __hip_bfloat16* wpb = wab + (size_t)3072 * 1024;             // 1024x1024
    __hip_bfloat16* qkv = wpb + (size_t)1024 * 1024;             // 4096x3072
    __hip_bfloat16* y   = qkv + (size_t)4096 * 3072;             // 4096x1024
    __hip_bfloat16* vt  = y   + (size_t)4096 * 1024;             // 2*16*64*2048

    cvt_f32_bf16_k<<<2048, 256, 0, stream>>>(x,      xb,  4096 * 1024);
    cvt_f32_bf16_k<<<1536, 256, 0, stream>>>(w_attn, wab, 3072 * 1024);
    cvt_f32_bf16_k<<<512,  256, 0, stream>>>(w_proj, wpb, 1024 * 1024);

    // qkv = xb @ wab^T : M=4096 N=3072 K=1024
    gemm_bt_mfma<false><<<dim3(24, 32), 256, 0, stream>>>(xb, wab, qkv, 4096, 3072, 1024);

    transpose_v<<<dim3(32, 16, 2), 256, 0, stream>>>(qkv, vt);
    attn_kernel<<<dim3(16, 16, 2), 256, 0, stream>>>(qkv, vt, y);

    // out = y @ wpb^T : M=4096 N=1024 K=1024 (fp32 out)
    gemm_bt_mfma<true><<<dim3(8, 32), 256, 0, stream>>>(y, wpb, out, 4096, 1024, 1024);
}